// Round 17
// baseline (269.488 us; speedup 1.0000x reference)
//
#include <hip/hip_runtime.h>
#include <hip/hip_bf16.h>
#include <math.h>

// Problem constants
#define Bb 2
#define Ss 2048
#define Dd 1024
#define Hh 16
#define FFf 4096
#define EPSf 1e-5f
#define SCALEf 0.03125f   // 1/sqrt(1024)
#define LOG2Ef 1.4426950408889634f
#define SCALE2f (SCALEf * LOG2Ef)
#define KSPLIT 2
#define NTILES ((Ss / KSPLIT) / 64)   // 16

typedef short s16x8 __attribute__((ext_vector_type(8)));
typedef short s16x4 __attribute__((ext_vector_type(4)));
typedef float f32x4 __attribute__((ext_vector_type(4)));
typedef float f32x16 __attribute__((ext_vector_type(16)));

// fp32 -> bf16 (RNE) raw bits
__device__ __forceinline__ short f2bs(float f) {
    union { float f; unsigned u; } v; v.f = f;
    const unsigned r = (v.u + 0x7FFFu + ((v.u >> 16) & 1u)) >> 16;
    return (short)r;
}
__device__ __forceinline__ float bs2f(short s) {
    union { unsigned u; float f; } v; v.u = ((unsigned)(unsigned short)s) << 16;
    return v.f;
}
__device__ __forceinline__ float gelu_exact(float v) {
    return 0.5f * v * (1.0f + erff(v * 0.7071067811865475f));
}
__device__ __forceinline__ void gload16(const void* g, void* l) {
    __builtin_amdgcn_global_load_lds(
        (const __attribute__((address_space(1))) unsigned int*)g,
        (__attribute__((address_space(3))) unsigned int*)l, 16, 0, 0);
}
__device__ __forceinline__ unsigned cvt_pk(float lo, float hi) {
    unsigned r;
    asm("v_cvt_pk_bf16_f32 %0, %1, %2" : "=v"(r) : "v"(lo), "v"(hi));
    return r;
}

// ---------------------------------------------------------------------------
// Fused prep: 6 weight transposes (fp32 -> bf16, W[K][N] -> Wt[N][K]) + mask*log2e
// ---------------------------------------------------------------------------
__global__ __launch_bounds__(256) void prep(const float* __restrict__ wq, const float* __restrict__ wk,
                                            const float* __restrict__ wv, const float* __restrict__ wo,
                                            const float* __restrict__ w1, const float* __restrict__ w2,
                                            const float* __restrict__ mask,
                                            short* __restrict__ qkvw_t, short* __restrict__ wot,
                                            short* __restrict__ w1t, short* __restrict__ w2t,
                                            float* __restrict__ msc) {
    const int blk = blockIdx.x;
    const int tid = threadIdx.x;
    if (blk >= 3072) {
#pragma unroll
        for (int j = 0; j < 16; ++j) msc[tid + j * 256] = mask[tid + j * 256] * LOG2Ef;
        return;
    }
    const float* W; short* Wt; int K, N, inner;
    if (blk < 1024) {
        const int which = blk >> 8; inner = blk & 255;
        K = 1024; N = 1024;
        W = (which == 0) ? wq : (which == 1) ? wk : (which == 2) ? wv : wo;
        Wt = (which < 3) ? qkvw_t + (size_t)which * 1024 * 1024 : wot;
    } else if (blk < 2048) {
        inner = blk - 1024; K = 1024; N = 4096; W = w1; Wt = w1t;
    } else {
        inner = blk - 2048; K = 4096; N = 1024; W = w2; Wt = w2t;
    }
    const int nbx = N / 64;
    const int bx = inner % nbx, by = inner / nbx;
    __shared__ short T[64][65];
    const int n0 = bx * 64, k0 = by * 64;
    const int c = tid & 63, rg = tid >> 6;
#pragma unroll
    for (int j = 0; j < 16; ++j) {
        const int r = rg * 16 + j;
        T[r][c] = f2bs(W[(size_t)(k0 + r) * N + n0 + c]);
    }
    __syncthreads();
#pragma unroll
    for (int j = 0; j < 16; ++j) {
        const int r = rg * 16 + j;
        Wt[(size_t)(n0 + r) * K + k0 + c] = T[c][r];
    }
}

// ---------------------------------------------------------------------------
// V transpose: QKV[tok][3072] (V cols 2048..3071) -> VT[b][h][d=64][s=2048]
// ---------------------------------------------------------------------------
__global__ __launch_bounds__(256) void vtranspose(const short* __restrict__ QKV,
                                                  short* __restrict__ VT) {
    __shared__ __align__(16) short T[64 * 144];
    const int t = threadIdx.x;
    const int bh = blockIdx.x;
    const int sc = blockIdx.y;
    const int b = bh >> 4, h = bh & 15;
#pragma unroll
    for (int i = 0; i < 4; ++i) {
        const int sl = i * 32 + (t >> 3);
        const int d0 = (t & 7) * 8;
        const s16x8 v = *(const s16x8*)&QKV[((size_t)(b * Ss + sc * 128 + sl)) * 3072 + 2048 + h * 64 + d0];
#pragma unroll
        for (int e = 0; e < 8; ++e) {
            const int d = d0 + e;
            T[(d * 144 + sl) ^ (((d >> 3) & 7) << 3)] = v[e];
        }
    }
    __syncthreads();
#pragma unroll
    for (int i = 0; i < 4; ++i) {
        const int d = i * 16 + (t >> 4);
        const int s0 = (t & 15) * 8;
        const s16x8 o = *(const s16x8*)&T[(d * 144 + s0) ^ (((d >> 3) & 7) << 3)];
        *(s16x8*)&VT[((size_t)(bh * 64 + d)) * 2048 + sc * 128 + s0] = o;
    }
}

// ---------------------------------------------------------------------------
// LayerNorm: fp32 in, bf16 out
// ---------------------------------------------------------------------------
__global__ __launch_bounds__(256) void layernorm_bf16(const float* __restrict__ X,
                                                      const float* __restrict__ g,
                                                      const float* __restrict__ bta,
                                                      short* __restrict__ Y) {
    __shared__ float red[8];
    const int row = blockIdx.x;
    const int tid = threadIdx.x;
    const size_t base = (size_t)row * Dd + tid * 4;
    const float4 xv = *(const float4*)&X[base];
    float s  = xv.x + xv.y + xv.z + xv.w;
    float sq = xv.x * xv.x + xv.y * xv.y + xv.z * xv.z + xv.w * xv.w;
#pragma unroll
    for (int o = 32; o >= 1; o >>= 1) {
        s  += __shfl_xor(s, o, 64);
        sq += __shfl_xor(sq, o, 64);
    }
    const int lane = tid & 63, wv = tid >> 6;
    if (lane == 0) { red[wv] = s; red[4 + wv] = sq; }
    __syncthreads();
    const float tot  = red[0] + red[1] + red[2] + red[3];
    const float totq = red[4] + red[5] + red[6] + red[7];
    const float mu  = tot * (1.0f / Dd);
    const float var = totq * (1.0f / Dd) - mu * mu;
    const float inv = 1.0f / sqrtf(var + EPSf);
    const float4 gv = *(const float4*)&g[tid * 4];
    const float4 bv = *(const float4*)&bta[tid * 4];
    s16x4 o;
    o[0] = f2bs((xv.x - mu) * inv * gv.x + bv.x);
    o[1] = f2bs((xv.y - mu) * inv * gv.y + bv.y);
    o[2] = f2bs((xv.z - mu) * inv * gv.z + bv.z);
    o[3] = f2bs((xv.w - mu) * inv * gv.w + bv.w);
    *(s16x4*)&Y[base] = o;
}

// ---------------------------------------------------------------------------
// Literal m97-structure GEMM (guide §5 step-3, 874 TF reference config):
// 128x128 tile, BK=32, 4 waves 2x2, SINGLE-buffered LDS, __syncthreads()
// (compiler-managed waitcnt/interleave), inline addresses, NO asm fences,
// NO swizzle, NO launch_bounds-min. Only additions vs m97: swapped operands
// (vectorized s16x4 C-stores) + XCD block swizzle.
// EPI: 0 = bf16 out, 1 = GELU + bf16 out.
// ---------------------------------------------------------------------------
template <int EPI>
__global__ __launch_bounds__(256) void gemm_m97(const short* __restrict__ A,
                                                const short* __restrict__ Bt,
                                                void* __restrict__ Cout,
                                                int M, int N, int K, int gx) {
    __shared__ short As[128 * 32];
    __shared__ short Bs[128 * 32];
    const int tid = threadIdx.x;
    const int w = tid >> 6, l = tid & 63;
    const int lr = l & 15, lg = l >> 4;
    const int wr = w >> 1, wc = w & 1;

    const int nwg = gridDim.x;
    const int bid = blockIdx.x;
    const int swz = (bid & 7) * (nwg >> 3) + (bid >> 3);
    const int bx = swz % gx, by = swz / gx;

    const int srow = l >> 2;        // 0..15
    const int skb  = (l & 3) * 8;   // 0,8,16,24
    const size_t arow0 = (size_t)(by * 128 + w * 32);
    const size_t brow0 = (size_t)(bx * 128 + w * 32);

    f32x4 acc[4][4] = {};

    for (int k0 = 0; k0 < K; k0 += 32) {
        __syncthreads();
#pragma unroll
        for (int j = 0; j < 2; ++j) {
            gload16(A + (arow0 + j * 16 + srow) * K + k0 + skb,
                    &As[(w * 32 + j * 16) * 32]);
            gload16(Bt + (brow0 + j * 16 + srow) * K + k0 + skb,
                    &Bs[(w * 32 + j * 16) * 32]);
        }
        __syncthreads();
        s16x8 a[4], b[4];
#pragma unroll
        for (int m = 0; m < 4; ++m)
            a[m] = *(const s16x8*)&As[(wr * 64 + m * 16 + lr) * 32 + lg * 8];
#pragma unroll
        for (int n = 0; n < 4; ++n)
            b[n] = *(const s16x8*)&Bs[(wc * 64 + n * 16 + lr) * 32 + lg * 8];
#pragma unroll
        for (int n = 0; n < 4; ++n)
#pragma unroll
            for (int m = 0; m < 4; ++m)
                acc[n][m] = __builtin_amdgcn_mfma_f32_16x16x32_bf16(b[n], a[m], acc[n][m], 0, 0, 0);
    }

    // swapped C/D layout: lane holds C[row=m*16+lr][col=n*16+lg*4+r]
    const int row0 = by * 128 + wr * 64;
    const int col0 = bx * 128 + wc * 64;
#pragma unroll
    for (int m = 0; m < 4; ++m) {
        const int row = row0 + m * 16 + lr;
#pragma unroll
        for (int n = 0; n < 4; ++n) {
            const int cb = col0 + n * 16 + lg * 4;
            s16x4 o;
#pragma unroll
            for (int r = 0; r < 4; ++r) {
                float v = acc[n][m][r];
                if (EPI == 1) v = gelu_exact(v);
                o[r] = f2bs(v);
            }
            *(s16x4*)&((short*)Cout)[(size_t)row * N + cb] = o;
        }
    }
}

// ---------------------------------------------------------------------------
// bf16 MFMA GEMM v4 (R15 config, for WO/W2): dbuf BK=64, drain schedule.
// ---------------------------------------------------------------------------
template <int BM, int BN, int BK, int EPI, int MW>
__global__ __launch_bounds__(256, MW) void gemm_v4(const short* __restrict__ A,
                                                   const short* __restrict__ Bt,
                                                   const float* __restrict__ R,
                                                   void* __restrict__ Cout,
                                                   int M, int N, int K, int gx) {
    constexpr int WM = BM / 2, WN = BN / 2;
    constexpr int MF = WM / 16, NF = WN / 16;
    constexpr int S   = BK / 8;
    constexpr int LPR = BK / 8;
    constexpr int RPI = 64 / LPR;
    constexpr int IPWA = (BM / 4) / RPI;
    constexpr int IPWB = (BN / 4) / RPI;
    __shared__ __align__(16) short As[2][BM * BK];
    __shared__ __align__(16) short Bs[2][BN * BK];

    const int tid = threadIdx.x;
    const int w = tid >> 6, l = tid & 63;
    const int lr = l & 15, lg = l >> 4;
    const int wr = w >> 1, wc = w & 1;

    const int nwg = gridDim.x;
    const int bid = blockIdx.x;
    const int swz = (bid & 7) * (nwg >> 3) + (bid >> 3);
    const int bx = swz % gx, by = swz / gx;

    const int lrow = l / LPR;
    const int sslot = ((l % LPR) ^ (((lrow * BK) >> 6) & (S - 1))) * 8;
    const size_t arow0 = (size_t)(by * BM);
    const size_t brow0 = (size_t)(bx * BN);

    f32x4 acc[NF][MF] = {};

    auto STAGE = [&](int bi, int k0) {
#pragma unroll
        for (int j = 0; j < IPWA; ++j) {
            const int r0 = w * (BM / 4) + j * RPI;
            gload16(A + (arow0 + r0 + lrow) * K + k0 + sslot, &As[bi][r0 * BK]);
        }
#pragma unroll
        for (int j = 0; j < IPWB; ++j) {
            const int r0 = w * (BN / 4) + j * RPI;
            gload16(Bt + (brow0 + r0 + lrow) * K + k0 + sslot, &Bs[bi][r0 * BK]);
        }
    };

    int aidx[BK / 32][MF], bidx[BK / 32][NF];
#pragma unroll
    for (int kk = 0; kk < BK / 32; ++kk) {
#pragma unroll
        for (int m = 0; m < MF; ++m) {
            const int r = wr * WM + m * 16 + lr;
            aidx[kk][m] = r * BK + ((kk * 4 + lg) ^ (((r * BK) >> 6) & (S - 1))) * 8;
        }
#pragma unroll
        for (int n = 0; n < NF; ++n) {
            const int r = wc * WN + n * 16 + lr;
            bidx[kk][n] = r * BK + ((kk * 4 + lg) ^ (((r * BK) >> 6) & (S - 1))) * 8;
        }
    }

    const int NKi = K / BK;
    STAGE(0, 0);

#pragma unroll 2
    for (int ks = 0; ks < NKi; ++ks) {
        const int cur = ks & 1;
        asm volatile("s_waitcnt vmcnt(0)" ::: "memory");
        __builtin_amdgcn_s_barrier();
        if (ks + 1 < NKi) STAGE(cur ^ 1, (ks + 1) * BK);

#pragma unroll
        for (int kk = 0; kk < BK / 32; ++kk) {
            s16x8 a[MF], b[NF];
#pragma unroll
            for (int m = 0; m < MF; ++m) a[m] = *(const s16x8*)&As[cur][aidx[kk][m]];
#pragma unroll
            for (int n = 0; n < NF; ++n) b[n] = *(const s16x8*)&Bs[cur][bidx[kk][n]];
#pragma unroll
            for (int n = 0; n < NF; ++n)
#pragma unroll
                for (int m = 0; m < MF; ++m)
                    acc[n][m] = __builtin_amdgcn_mfma_f32_16x16x32_bf16(b[n], a[m], acc[n][m], 0, 0, 0);
        }
    }

    const int row0 = by * BM + wr * WM;
    const int col0 = bx * BN + wc * WN;
#pragma unroll
    for (int m = 0; m < MF; ++m) {
        const int row = row0 + m * 16 + lr;
#pragma unroll
        for (int n = 0; n < NF; ++n) {
            const int cb = col0 + n * 16 + lg * 4;
            if (EPI == 2) {
                float* C = (float*)Cout;
                const f32x4 r4 = *(const f32x4*)&R[(size_t)row * N + cb];
                f32x4 o;
#pragma unroll
                for (int r = 0; r < 4; ++r) o[r] = acc[n][m][r] + r4[r];
                *(f32x4*)&C[(size_t)row * N + cb] = o;
            } else {
                s16x4 o;
#pragma unroll
                for (int r = 0; r < 4; ++r) {
                    float v = acc[n][m][r];
                    if (EPI == 1) v = gelu_exact(v);
                    o[r] = f2bs(v);
                }
                *(s16x4*)&((short*)Cout)[(size_t)row * N + cb] = o;
            }
        }
    }
}

// ---------------------------------------------------------------------------
// Flash attention: 32x32x16 MFMA, swapped operands, in-register P.
// Block = 4 waves x 32 q = 128 q. KSPLIT=2, grid 1024 (4/CU), XCD-swizzled.
// ---------------------------------------------------------------------------
__global__ __launch_bounds__(256, 4) void attn_split(const short* __restrict__ QKV,
                                                     const short* __restrict__ VT,
                                                     const float* __restrict__ MSC,
                                                     short* __restrict__ Opart,
                                                     float2* __restrict__ ML) {
    __shared__ __align__(16) short Kbuf[2][64 * 64];
    __shared__ __align__(16) short Vbuf[2][64 * 64];

    const int tid = threadIdx.x;
    const int w = tid >> 6, l = tid & 63;
    const int col = l & 31;
    const int hi = l >> 5;

    const int bid0 = blockIdx.x;
    const int bid = (bid0 & 7) * (gridDim.x >> 3) + (bid0 >> 3);
    const int part = bid >> 9;
    const int inner = bid & 511;
    const int qt = inner & 15, h = (inner >> 4) & 15, b = inner >> 8;
    const int q0 = qt * 128 + w * 32;
    const int k_base = part * (Ss / KSPLIT);

    s16x8 qf[4];
    {
        const short* qsrc = QKV + ((size_t)(b * Ss + q0 + col)) * 3072 + h * 64 + hi * 8;
        qf[0] = *(const s16x8*)(qsrc);
        qf[1] = *(const s16x8*)(qsrc + 16);
        qf[2] = *(const s16x8*)(qsrc + 32);
        qf[3] = *(const s16x8*)(qsrc + 48);
    }

    const int sr   = l >> 3;
    const int slot = ((l & 7) ^ (sr & 7)) * 8;
    const short* kg = QKV + (size_t)(b * Ss) * 3072 + 1024 + h * 64 + (size_t)sr * 3072 + slot;
    const short* vg = VT + ((size_t)(b * Hh + h) * 64 + sr) * 2048 + k_base + slot;
    const float* mscb = MSC + (size_t)b * Ss + k_base;

    int kidx[2][4], vidx[2][2][2];
#pragma unroll
    for (int sub = 0; sub < 2; ++sub) {
        const int rk = sub * 32 + col;
#pragma unroll
        for (int dd = 0; dd < 4; ++dd)
            kidx[sub][dd] = rk * 64 + ((2 * dd + hi) ^ (rk & 7)) * 8;
#pragma unroll
        for (int kk = 0; kk < 2; ++kk)
#pragma unroll
            for (int dt = 0; dt < 2; ++dt) {
                const int rv = dt * 32 + col;
                vidx[sub][kk][dt] = rv * 64 + ((sub * 4 + 2 * kk + hi) ^ (rv & 7)) * 8;
            }
    }

    f32x16 o_acc[2] = {};
    float m_used = -1e30f, l_run = 0.0f;

    auto STAGE = [&](int bi, int t) {
#pragma unroll
        for (int j = 0; j < 2; ++j) {
            const int r0 = w * 16 + j * 8;
            gload16(kg + (size_t)(k_base + t * 64 + r0) * 3072, &Kbuf[bi][r0 * 64]);
            gload16(vg + (size_t)r0 * 2048 + t * 64,             &Vbuf[bi][r0 * 64]);
        }
    };

    STAGE(0, 0);

#pragma unroll 2
    for (int i = 0; i < NTILES; ++i) {
        const int cur = i & 1;
        asm volatile("s_waitcnt vmcnt(0)" ::: "memory");
        __builtin_amdgcn_s_barrier();
        if (i + 1 < NTILES) STAGE(cur ^ 1, i + 1);

#pragma unroll
        for (int sub = 0; sub < 2; ++sub) {
            f32x16 sa = {};
#pragma unroll
            for (int dd = 0; dd < 4; ++dd) {
                const s16x8 kf = *(const s16x8*)&Kbuf[cur][kidx[sub][dd]];
                sa = __builtin_amdgcn_mfma_f32_32x32x16_bf16(kf, qf[dd], sa, 0, 0, 0);
            }

#pragma unroll
            for (int c4 = 0; c4 < 4; ++c4) {
                const f32x4 mv = *(const f32x4*)&mscb[i * 64 + sub * 32 + 8 * c4 + 4 * hi];
#pragma unroll
                for (int rr = 0; rr < 4; ++rr) sa[c4 * 4 + rr] = sa[c4 * 4 + rr] * SCALE2f + mv[rr];
            }
            float t8[8], t4[4];
#pragma unroll
            for (int r = 0; r < 8; ++r) t8[r] = fmaxf(sa[2 * r], sa[2 * r + 1]);
#pragma unroll
            for (int r = 0; r < 4; ++r) t4[r] = fmaxf(t8[2 * r], t8[2 * r + 1]);
            float tmax = fmaxf(fmaxf(t4[0], t4[1]), fmaxf(t4[2], t4[3]));
            {
                unsigned a = __float_as_uint(tmax), bq = __float_as_uint(tmax);
                asm volatile("v_permlane32_swap_b32 %0, %1" : "+v"(a), "+v"(bq));
                tmax = fmaxf(tmax, __uint_as_float(hi ? a : bq));
            }
            if (__any(tmax > m_used + 8.0f)) {
                const float nm = fmaxf(m_used, tmax);
                const float corr = __builtin_amdgcn_exp2f(m_used - nm);
                m_used = nm;
                l_run *= corr;
#pragma unroll
                for (int dt = 0; dt < 2; ++dt)
#pragma unroll
                    for (int r = 0; r < 16; ++r) o_acc[dt][r] *= corr;
            }

            unsigned wd[8];
            float s8[8];
#pragma unroll
            for (int m8 = 0; m8 < 8; ++m8) {
                const float p0 = __builtin_amdgcn_exp2f(sa[2 * m8]     - m_used);
                const float p1 = __builtin_amdgcn_exp2f(sa[2 * m8 + 1] - m_used);
                s8[m8] = p0 + p1;
                wd[m8] = cvt_pk(p0, p1);
            }
            float s4[4];
#pragma unroll
            for (int r = 0; r < 4; ++r) s4[r] = s8[2 * r] + s8[2 * r + 1];
            l_run += (s4[0] + s4[1]) + (s4[2] + s4[3]);

            unsigned f00 = wd[0], f02 = wd[2];
            asm volatile("v_permlane32_swap_b32 %0, %1" : "+v"(f00), "+v"(f02));
            unsigned f01 = wd[1], f03 = wd[3];
            asm volatile("v_permlane32_swap_b32 %0, %1" : "+v"(f01), "+v"(f03));
            unsigned f10 = wd[4], f12 = wd[6];
            asm volatile("v_permlane32_swap_b32 %0, %1" : "+v"(f10), "+v"(f12));
            unsigned f11 = wd[5], f13 = wd[7];
            asm volatile("v_permlane32_swap_b32 %0, %1" : "+v"(f11), "+v"(f13));
            union { unsigned u[4]; s16x8 v; } pf0, pf1;
            pf0.u[0] = f00; pf0.u[1] = f01; pf0.u[2] = f02; pf0.u[3] = f03;
            pf1.u[0] = f10; pf1.u[1] = f11; pf1.u[2] = f12; pf1.u[3] = f13;

#pragma unroll
            for (int dt = 0; dt < 2; ++dt) {
                const s16x8 v0 = *(const s16x8*)&Vbuf[cur][vidx[sub][0][dt]];
                const s16x8 v1 = *(const s16x8*)&Vbuf[cur][vidx[sub][1][dt]];
                o_acc[dt] = __builtin_amdgcn_mfma_f32_32x32x16_bf16(v0, pf0.v, o_acc[dt], 0, 0, 0);
                o_acc[dt] = __builtin_amdgcn_mfma_f32_32x32x16_bf16(v1, pf1.v, o_acc[dt], 0, 0, 0);
            }
        }
    }

    float l_tot;
    {
        unsigned a = __float_as_uint(l_run), bq = __float_as_uint(l_run);
        asm volatile("v_permlane32_swap_b32 %0, %1" : "+v"(a), "+v"(bq));
        l_tot = l_run + __uint_as_float(hi ? a : bq);
    }
    const size_t tok = (size_t)(b * Ss + q0 + col);
    if (hi == 0) {
        ML[(size_t)part * (Bb * Ss * Hh) + tok * Hh + h] = make_float2(m_used, l_tot);
    }
    short* obase = Opart + (size_t)part * (Bb * Ss) * Dd + tok * Dd + h * 64;
#pragma unroll
    for (int dt = 0; dt < 2; ++dt) {
#pragma unroll
        for (int c4 = 0; c4 < 4; ++c4) {
            s16x4 ov;
#pragma unroll
            for (int rr = 0; rr < 4; ++rr) ov[rr] = f2bs(o_acc[dt][c4 * 4 + rr]);
            *(s16x4*)&obase[dt * 32 + 8 * c4 + 4 * hi] = ov;
        }
    }
}

// ---------------------------------------------------------------------------
// KSPLIT combine
// ---------------------------------------------------------------------------
__global__ __launch_bounds__(256) void attn_combine(const short* __restrict__ Opart,
                                                    const float2* __restrict__ ML,
                                                    short* __restrict__ Oa) {
    const int tok = blockIdx.x;
    const int t = threadIdx.x;
    const int h = t >> 4;
    const int d = (t & 15) * 4;
    float2 ml[KSPLIT];
    float M = -1e30f;
#pragma unroll
    for (int p = 0; p < KSPLIT; ++p) {
        ml[p] = ML[(size_t)p * (Bb * Ss * Hh) + (size_t)tok * Hh + h];
        M = fmaxf(M, ml[p].x);
    }
    float a[KSPLIT], denom = 0.0f;
#pragma unroll
    for (int p = 0; p < KSPLIT; ++p) {
        a[p] = __builtin_amdgcn_exp2f(ml[p].x - M);
        denom += ml[p].y * a[p];
    }
    const float inv = 1.0f / denom;
    const size_t off = (size_t)tok * Dd + h * 64 + d;
    float acc[4] = {};
#pragma unroll
    for (int p = 0; p < KSPLIT; ++p) {
        const s16x4 o4 = *(const s16x4*)&Opart[(size_t)p * (Bb * Ss) * Dd + off];
#pragma unroll
        for (int r = 0; r < 4; ++r) acc[r] += bs2f(o4[r]) * a[p];
    }
    s16x4 o;
#pragma unroll
    for (int r = 0; r < 4; ++r) o[r] = f2bs(acc[r] * inv);
    *(s16x4*)&Oa[off] = o;
}

// ---------------------------------------------------------------------------
extern "C" void kernel_launch(void* const* d_in, const int* in_sizes, int n_in,
                              void* d_out, int out_size, void* d_ws, size_t ws_size,
                              hipStream_t stream) {
    const float* x    = (const float*)d_in[0];
    const float* mask = (const float*)d_in[1];
    const float* wq   = (const float*)d_in[2];
    const float* wk   = (const float*)d_in[3];
    const float* wv   = (const float*)d_in[4];
    const float* wo   = (const float*)d_in[5];
    const float* w1   = (const float*)d_in[6];
    const float* w2   = (const float*)d_in[7];
    const float* ln1g = (const float*)d_in[8];
    const float* ln1b = (const float*)d_in[9];
    const float* ln2g = (const float*)d_in[10];
    const float* ln2b = (const float*)d_in[11];
    float* out = (float*)d_out;

    char* p = (char*)d_ws;
    short* qkvw_t = (short*)p; p += (size_t)3072 * 1024 * 2;   // 6 MB
    short* wot    = (short*)p; p += (size_t)1024 * 1024 * 2;   // 2 MB
    short* w1t    = (short*)p; p += (size_t)4096 * 1024 * 2;   // 8 MB
    short* w2t    = (short*)p; p += (size_t)1024 * 4096 * 2;   // 8 MB
    short* y_bf   = (short*)p; p += (size_t)4096 * 1024 * 2;   // 8 MB
    short* qkv    = (short*)p; p += (size_t)4096 * 3072 * 2;   // 24 MB
    short* attn_b = (short*)p; p += (size_t)4096 * 1024 * 2;   // 8 MB
    short* y2_bf  = (short*)p; p += (size_t)4096 * 1024 * 2;   // 8 MB
    char*  hregion = p;        p += (size_t)4096 * 4096 * 2;   // 32 MB
    float* msc    = (float*)p; p += (size_t)Bb * Ss * 4;       // 16 KB

    short*  h_bf   = (short*)hregion;
    short*  o_part = (short*)hregion;           // KSPLIT x 8 MB (dead before FFN)
    short*  vt     = y_bf;                      // y_bf dead after QKV GEMM
    float2* ml     = (float2*)qkvw_t;           // qkvw_t dead after QKV GEMM

    const int M = Bb * Ss;  // 4096

    prep<<<3073, 256, 0, stream>>>(wq, wk, wv, wo, w1, w2, mask, qkvw_t, wot, w1t, w2t, msc);
    layernorm_bf16<<<M, 256, 0, stream>>>(x, ln1g, ln1b, y_bf);
    // QKV: literal-m97 128x128 single-buffer, grid 768
    gemm_m97<0><<<768, 256, 0, stream>>>(y_bf, qkvw_t, qkv, M, 3072, 1024, 24);
    vtranspose<<<dim3(32, 16), 256, 0, stream>>>(qkv, vt);
    // attention: KSPLIT=2, grid 1024 (4/CU, 1 round), XCD-swizzled
    attn_split<<<KSPLIT * 512, 256, 0, stream>>>(qkv, vt, msc, o_part, ml);
    attn_combine<<<M, 256, 0, stream>>>(o_part, ml, attn_b);
    // WO: 64x64, BK=64, MW=4, grid 1024
    gemm_v4<64, 64, 64, 2, 4><<<1024, 256, 0, stream>>>(attn_b, wot, x, out, M, 1024, 1024, 16);
    layernorm_bf16<<<M, 256, 0, stream>>>(out, ln2g, ln2b, y2_bf);
    // W1: literal-m97 128x128 single-buffer + GELU, grid 1024
    gemm_m97<1><<<1024, 256, 0, stream>>>(y2_bf, w1t, h_bf, M, 4096, 1024, 32);
    // W2: 64x64, BK=64, MW=4, grid 1024, K=4096
    gemm_v4<64, 64, 64, 2, 4><<<1024, 256, 0, stream>>>(h_bf, w2t, out, out, M, 1024, 4096, 16);
}

// Round 18
// 243.639 us; speedup vs baseline: 1.1061x; 1.1061x over previous
//
#include <hip/hip_runtime.h>
#include <hip/hip_bf16.h>
#include <math.h>

// Problem constants
#define Bb 2
#define Ss 2048
#define Dd 1024
#define Hh 16
#define FFf 4096
#define EPSf 1e-5f
#define SCALEf 0.03125f   // 1/sqrt(1024)
#define LOG2Ef 1.4426950408889634f
#define SCALE2f (SCALEf * LOG2Ef)
#define KSPLIT 2
#define NTILES ((Ss / KSPLIT) / 64)   // 16

typedef short s16x8 __attribute__((ext_vector_type(8)));
typedef short s16x4 __attribute__((ext_vector_type(4)));
typedef float f32x4 __attribute__((ext_vector_type(4)));
typedef float f32x16 __attribute__((ext_vector_type(16)));

// fp32 -> bf16 (RNE) raw bits
__device__ __forceinline__ short f2bs(float f) {
    union { float f; unsigned u; } v; v.f = f;
    const unsigned r = (v.u + 0x7FFFu + ((v.u >> 16) & 1u)) >> 16;
    return (short)r;
}
__device__ __forceinline__ float bs2f(short s) {
    union { unsigned u; float f; } v; v.u = ((unsigned)(unsigned short)s) << 16;
    return v.f;
}
__device__ __forceinline__ float gelu_exact(float v) {
    return 0.5f * v * (1.0f + erff(v * 0.7071067811865475f));
}
__device__ __forceinline__ void gload16(const void* g, void* l) {
    __builtin_amdgcn_global_load_lds(
        (const __attribute__((address_space(1))) unsigned int*)g,
        (__attribute__((address_space(3))) unsigned int*)l, 16, 0, 0);
}
__device__ __forceinline__ unsigned cvt_pk(float lo, float hi) {
    unsigned r;
    asm("v_cvt_pk_bf16_f32 %0, %1, %2" : "=v"(r) : "v"(lo), "v"(hi));
    return r;
}

// ---------------------------------------------------------------------------
// Fused prep: 6 weight transposes (fp32 -> bf16, W[K][N] -> Wt[N][K]) + mask*log2e
// ---------------------------------------------------------------------------
__global__ __launch_bounds__(256) void prep(const float* __restrict__ wq, const float* __restrict__ wk,
                                            const float* __restrict__ wv, const float* __restrict__ wo,
                                            const float* __restrict__ w1, const float* __restrict__ w2,
                                            const float* __restrict__ mask,
                                            short* __restrict__ qkvw_t, short* __restrict__ wot,
                                            short* __restrict__ w1t, short* __restrict__ w2t,
                                            float* __restrict__ msc) {
    const int blk = blockIdx.x;
    const int tid = threadIdx.x;
    if (blk >= 3072) {
#pragma unroll
        for (int j = 0; j < 16; ++j) msc[tid + j * 256] = mask[tid + j * 256] * LOG2Ef;
        return;
    }
    const float* W; short* Wt; int K, N, inner;
    if (blk < 1024) {
        const int which = blk >> 8; inner = blk & 255;
        K = 1024; N = 1024;
        W = (which == 0) ? wq : (which == 1) ? wk : (which == 2) ? wv : wo;
        Wt = (which < 3) ? qkvw_t + (size_t)which * 1024 * 1024 : wot;
    } else if (blk < 2048) {
        inner = blk - 1024; K = 1024; N = 4096; W = w1; Wt = w1t;
    } else {
        inner = blk - 2048; K = 4096; N = 1024; W = w2; Wt = w2t;
    }
    const int nbx = N / 64;
    const int bx = inner % nbx, by = inner / nbx;
    __shared__ short T[64][65];
    const int n0 = bx * 64, k0 = by * 64;
    const int c = tid & 63, rg = tid >> 6;
#pragma unroll
    for (int j = 0; j < 16; ++j) {
        const int r = rg * 16 + j;
        T[r][c] = f2bs(W[(size_t)(k0 + r) * N + n0 + c]);
    }
    __syncthreads();
#pragma unroll
    for (int j = 0; j < 16; ++j) {
        const int r = rg * 16 + j;
        Wt[(size_t)(n0 + r) * K + k0 + c] = T[c][r];
    }
}

// ---------------------------------------------------------------------------
// V transpose: QKV[tok][3072] (V cols 2048..3071) -> VT[b][h][d=64][s=2048]
// ---------------------------------------------------------------------------
__global__ __launch_bounds__(256) void vtranspose(const short* __restrict__ QKV,
                                                  short* __restrict__ VT) {
    __shared__ __align__(16) short T[64 * 144];
    const int t = threadIdx.x;
    const int bh = blockIdx.x;
    const int sc = blockIdx.y;
    const int b = bh >> 4, h = bh & 15;
#pragma unroll
    for (int i = 0; i < 4; ++i) {
        const int sl = i * 32 + (t >> 3);
        const int d0 = (t & 7) * 8;
        const s16x8 v = *(const s16x8*)&QKV[((size_t)(b * Ss + sc * 128 + sl)) * 3072 + 2048 + h * 64 + d0];
#pragma unroll
        for (int e = 0; e < 8; ++e) {
            const int d = d0 + e;
            T[(d * 144 + sl) ^ (((d >> 3) & 7) << 3)] = v[e];
        }
    }
    __syncthreads();
#pragma unroll
    for (int i = 0; i < 4; ++i) {
        const int d = i * 16 + (t >> 4);
        const int s0 = (t & 15) * 8;
        const s16x8 o = *(const s16x8*)&T[(d * 144 + s0) ^ (((d >> 3) & 7) << 3)];
        *(s16x8*)&VT[((size_t)(bh * 64 + d)) * 2048 + sc * 128 + s0] = o;
    }
}

// ---------------------------------------------------------------------------
// LayerNorm: fp32 in, bf16 out
// ---------------------------------------------------------------------------
__global__ __launch_bounds__(256) void layernorm_bf16(const float* __restrict__ X,
                                                      const float* __restrict__ g,
                                                      const float* __restrict__ bta,
                                                      short* __restrict__ Y) {
    __shared__ float red[8];
    const int row = blockIdx.x;
    const int tid = threadIdx.x;
    const size_t base = (size_t)row * Dd + tid * 4;
    const float4 xv = *(const float4*)&X[base];
    float s  = xv.x + xv.y + xv.z + xv.w;
    float sq = xv.x * xv.x + xv.y * xv.y + xv.z * xv.z + xv.w * xv.w;
#pragma unroll
    for (int o = 32; o >= 1; o >>= 1) {
        s  += __shfl_xor(s, o, 64);
        sq += __shfl_xor(sq, o, 64);
    }
    const int lane = tid & 63, wv = tid >> 6;
    if (lane == 0) { red[wv] = s; red[4 + wv] = sq; }
    __syncthreads();
    const float tot  = red[0] + red[1] + red[2] + red[3];
    const float totq = red[4] + red[5] + red[6] + red[7];
    const float mu  = tot * (1.0f / Dd);
    const float var = totq * (1.0f / Dd) - mu * mu;
    const float inv = 1.0f / sqrtf(var + EPSf);
    const float4 gv = *(const float4*)&g[tid * 4];
    const float4 bv = *(const float4*)&bta[tid * 4];
    s16x4 o;
    o[0] = f2bs((xv.x - mu) * inv * gv.x + bv.x);
    o[1] = f2bs((xv.y - mu) * inv * gv.y + bv.y);
    o[2] = f2bs((xv.z - mu) * inv * gv.z + bv.z);
    o[3] = f2bs((xv.w - mu) * inv * gv.w + bv.w);
    *(s16x4*)&Y[base] = o;
}

// ---------------------------------------------------------------------------
// bf16 MFMA GEMM v4: C[M,N] = A[M,K] @ Bt[N,K]^T
// Double-buffered LDS, {vmcnt(0); barrier; STAGE(next); compute}.
// MW=3 on 128^2 tiles; BK=64 on 64^2 tiles (halved drains).
// XOR swizzle (2-way max = free), swapped operands, XCD swizzle.
// ---------------------------------------------------------------------------
template <int BM, int BN, int BK, int EPI, int MW>
__global__ __launch_bounds__(256, MW) void gemm_v4(const short* __restrict__ A,
                                                   const short* __restrict__ Bt,
                                                   const float* __restrict__ R,
                                                   void* __restrict__ Cout,
                                                   int M, int N, int K, int gx) {
    constexpr int WM = BM / 2, WN = BN / 2;
    constexpr int MF = WM / 16, NF = WN / 16;
    constexpr int S   = BK / 8;
    constexpr int LPR = BK / 8;
    constexpr int RPI = 64 / LPR;
    constexpr int IPWA = (BM / 4) / RPI;
    constexpr int IPWB = (BN / 4) / RPI;
    __shared__ __align__(16) short As[2][BM * BK];
    __shared__ __align__(16) short Bs[2][BN * BK];

    const int tid = threadIdx.x;
    const int w = tid >> 6, l = tid & 63;
    const int lr = l & 15, lg = l >> 4;
    const int wr = w >> 1, wc = w & 1;

    const int nwg = gridDim.x;
    const int bid = blockIdx.x;
    const int swz = (bid & 7) * (nwg >> 3) + (bid >> 3);
    const int bx = swz % gx, by = swz / gx;

    const int lrow = l / LPR;
    const int sslot = ((l % LPR) ^ (((lrow * BK) >> 6) & (S - 1))) * 8;
    const size_t arow0 = (size_t)(by * BM);
    const size_t brow0 = (size_t)(bx * BN);

    f32x4 acc[NF][MF] = {};

    auto STAGE = [&](int bi, int k0) {
#pragma unroll
        for (int j = 0; j < IPWA; ++j) {
            const int r0 = w * (BM / 4) + j * RPI;
            gload16(A + (arow0 + r0 + lrow) * K + k0 + sslot, &As[bi][r0 * BK]);
        }
#pragma unroll
        for (int j = 0; j < IPWB; ++j) {
            const int r0 = w * (BN / 4) + j * RPI;
            gload16(Bt + (brow0 + r0 + lrow) * K + k0 + sslot, &Bs[bi][r0 * BK]);
        }
    };

    // precompute LDS fragment indices (loop-invariant)
    int aidx[BK / 32][MF], bidx[BK / 32][NF];
#pragma unroll
    for (int kk = 0; kk < BK / 32; ++kk) {
#pragma unroll
        for (int m = 0; m < MF; ++m) {
            const int r = wr * WM + m * 16 + lr;
            aidx[kk][m] = r * BK + ((kk * 4 + lg) ^ (((r * BK) >> 6) & (S - 1))) * 8;
        }
#pragma unroll
        for (int n = 0; n < NF; ++n) {
            const int r = wc * WN + n * 16 + lr;
            bidx[kk][n] = r * BK + ((kk * 4 + lg) ^ (((r * BK) >> 6) & (S - 1))) * 8;
        }
    }

    const int NKi = K / BK;
    STAGE(0, 0);

#pragma unroll 2
    for (int ks = 0; ks < NKi; ++ks) {
        const int cur = ks & 1;
        asm volatile("s_waitcnt vmcnt(0)" ::: "memory");
        __builtin_amdgcn_s_barrier();
        if (ks + 1 < NKi) STAGE(cur ^ 1, (ks + 1) * BK);

#pragma unroll
        for (int kk = 0; kk < BK / 32; ++kk) {
            s16x8 a[MF], b[NF];
#pragma unroll
            for (int m = 0; m < MF; ++m) a[m] = *(const s16x8*)&As[cur][aidx[kk][m]];
#pragma unroll
            for (int n = 0; n < NF; ++n) b[n] = *(const s16x8*)&Bs[cur][bidx[kk][n]];
#pragma unroll
            for (int n = 0; n < NF; ++n)
#pragma unroll
                for (int m = 0; m < MF; ++m)
                    acc[n][m] = __builtin_amdgcn_mfma_f32_16x16x32_bf16(b[n], a[m], acc[n][m], 0, 0, 0);
        }
    }

    const int row0 = by * BM + wr * WM;
    const int col0 = bx * BN + wc * WN;
#pragma unroll
    for (int m = 0; m < MF; ++m) {
        const int row = row0 + m * 16 + lr;
#pragma unroll
        for (int n = 0; n < NF; ++n) {
            const int cb = col0 + n * 16 + lg * 4;
            if (EPI == 2) {
                float* C = (float*)Cout;
                const f32x4 r4 = *(const f32x4*)&R[(size_t)row * N + cb];
                f32x4 o;
#pragma unroll
                for (int r = 0; r < 4; ++r) o[r] = acc[n][m][r] + r4[r];
                *(f32x4*)&C[(size_t)row * N + cb] = o;
            } else {
                s16x4 o;
#pragma unroll
                for (int r = 0; r < 4; ++r) {
                    float v = acc[n][m][r];
                    if (EPI == 1) v = gelu_exact(v);
                    o[r] = f2bs(v);
                }
                *(s16x4*)&((short*)Cout)[(size_t)row * N + cb] = o;
            }
        }
    }
}

// ---------------------------------------------------------------------------
// Flash attention: 32x32x16 MFMA, swapped operands, in-register P.
// Block = 4 waves x 32 q = 128 q. KSPLIT=2, grid 1024 (4/CU), XCD-swizzled.
// setprio(1) around MFMA clusters (T5: positive for attn's role-diverse waves).
// ---------------------------------------------------------------------------
__global__ __launch_bounds__(256, 4) void attn_split(const short* __restrict__ QKV,
                                                     const short* __restrict__ VT,
                                                     const float* __restrict__ MSC,
                                                     short* __restrict__ Opart,
                                                     float2* __restrict__ ML) {
    __shared__ __align__(16) short Kbuf[2][64 * 64];
    __shared__ __align__(16) short Vbuf[2][64 * 64];

    const int tid = threadIdx.x;
    const int w = tid >> 6, l = tid & 63;
    const int col = l & 31;
    const int hi = l >> 5;

    const int bid0 = blockIdx.x;
    const int bid = (bid0 & 7) * (gridDim.x >> 3) + (bid0 >> 3);
    const int part = bid >> 9;
    const int inner = bid & 511;
    const int qt = inner & 15, h = (inner >> 4) & 15, b = inner >> 8;
    const int q0 = qt * 128 + w * 32;
    const int k_base = part * (Ss / KSPLIT);

    s16x8 qf[4];
    {
        const short* qsrc = QKV + ((size_t)(b * Ss + q0 + col)) * 3072 + h * 64 + hi * 8;
        qf[0] = *(const s16x8*)(qsrc);
        qf[1] = *(const s16x8*)(qsrc + 16);
        qf[2] = *(const s16x8*)(qsrc + 32);
        qf[3] = *(const s16x8*)(qsrc + 48);
    }

    const int sr   = l >> 3;
    const int slot = ((l & 7) ^ (sr & 7)) * 8;
    const short* kg = QKV + (size_t)(b * Ss) * 3072 + 1024 + h * 64 + (size_t)sr * 3072 + slot;
    const short* vg = VT + ((size_t)(b * Hh + h) * 64 + sr) * 2048 + k_base + slot;
    const float* mscb = MSC + (size_t)b * Ss + k_base;

    int kidx[2][4], vidx[2][2][2];
#pragma unroll
    for (int sub = 0; sub < 2; ++sub) {
        const int rk = sub * 32 + col;
#pragma unroll
        for (int dd = 0; dd < 4; ++dd)
            kidx[sub][dd] = rk * 64 + ((2 * dd + hi) ^ (rk & 7)) * 8;
#pragma unroll
        for (int kk = 0; kk < 2; ++kk)
#pragma unroll
            for (int dt = 0; dt < 2; ++dt) {
                const int rv = dt * 32 + col;
                vidx[sub][kk][dt] = rv * 64 + ((sub * 4 + 2 * kk + hi) ^ (rv & 7)) * 8;
            }
    }

    f32x16 o_acc[2] = {};
    float m_used = -1e30f, l_run = 0.0f;

    auto STAGE = [&](int bi, int t) {
#pragma unroll
        for (int j = 0; j < 2; ++j) {
            const int r0 = w * 16 + j * 8;
            gload16(kg + (size_t)(k_base + t * 64 + r0) * 3072, &Kbuf[bi][r0 * 64]);
            gload16(vg + (size_t)r0 * 2048 + t * 64,             &Vbuf[bi][r0 * 64]);
        }
    };

    STAGE(0, 0);

#pragma unroll 2
    for (int i = 0; i < NTILES; ++i) {
        const int cur = i & 1;
        asm volatile("s_waitcnt vmcnt(0)" ::: "memory");
        __builtin_amdgcn_s_barrier();
        if (i + 1 < NTILES) STAGE(cur ^ 1, i + 1);

#pragma unroll
        for (int sub = 0; sub < 2; ++sub) {
            f32x16 sa = {};
            __builtin_amdgcn_s_setprio(1);
#pragma unroll
            for (int dd = 0; dd < 4; ++dd) {
                const s16x8 kf = *(const s16x8*)&Kbuf[cur][kidx[sub][dd]];
                sa = __builtin_amdgcn_mfma_f32_32x32x16_bf16(kf, qf[dd], sa, 0, 0, 0);
            }
            __builtin_amdgcn_s_setprio(0);

#pragma unroll
            for (int c4 = 0; c4 < 4; ++c4) {
                const f32x4 mv = *(const f32x4*)&mscb[i * 64 + sub * 32 + 8 * c4 + 4 * hi];
#pragma unroll
                for (int rr = 0; rr < 4; ++rr) sa[c4 * 4 + rr] = sa[c4 * 4 + rr] * SCALE2f + mv[rr];
            }
            float t8[8], t4[4];
#pragma unroll
            for (int r = 0; r < 8; ++r) t8[r] = fmaxf(sa[2 * r], sa[2 * r + 1]);
#pragma unroll
            for (int r = 0; r < 4; ++r) t4[r] = fmaxf(t8[2 * r], t8[2 * r + 1]);
            float tmax = fmaxf(fmaxf(t4[0], t4[1]), fmaxf(t4[2], t4[3]));
            {
                unsigned a = __float_as_uint(tmax), bq = __float_as_uint(tmax);
                asm volatile("v_permlane32_swap_b32 %0, %1" : "+v"(a), "+v"(bq));
                tmax = fmaxf(tmax, __uint_as_float(hi ? a : bq));
            }
            if (__any(tmax > m_used + 8.0f)) {
                const float nm = fmaxf(m_used, tmax);
                const float corr = __builtin_amdgcn_exp2f(m_used - nm);
                m_used = nm;
                l_run *= corr;
#pragma unroll
                for (int dt = 0; dt < 2; ++dt)
#pragma unroll
                    for (int r = 0; r < 16; ++r) o_acc[dt][r] *= corr;
            }

            unsigned wd[8];
            float s8[8];
#pragma unroll
            for (int m8 = 0; m8 < 8; ++m8) {
                const float p0 = __builtin_amdgcn_exp2f(sa[2 * m8]     - m_used);
                const float p1 = __builtin_amdgcn_exp2f(sa[2 * m8 + 1] - m_used);
                s8[m8] = p0 + p1;
                wd[m8] = cvt_pk(p0, p1);
            }
            float s4[4];
#pragma unroll
            for (int r = 0; r < 4; ++r) s4[r] = s8[2 * r] + s8[2 * r + 1];
            l_run += (s4[0] + s4[1]) + (s4[2] + s4[3]);

            unsigned f00 = wd[0], f02 = wd[2];
            asm volatile("v_permlane32_swap_b32 %0, %1" : "+v"(f00), "+v"(f02));
            unsigned f01 = wd[1], f03 = wd[3];
            asm volatile("v_permlane32_swap_b32 %0, %1" : "+v"(f01), "+v"(f03));
            unsigned f10 = wd[4], f12 = wd[6];
            asm volatile("v_permlane32_swap_b32 %0, %1" : "+v"(f10), "+v"(f12));
            unsigned f11 = wd[5], f13 = wd[7];
            asm volatile("v_permlane32_swap_b32 %0, %1" : "+v"(f11), "+v"(f13));
            union { unsigned u[4]; s16x8 v; } pf0, pf1;
            pf0.u[0] = f00; pf0.u[1] = f01; pf0.u[2] = f02; pf0.u[3] = f03;
            pf1.u[0] = f10; pf1.u[1] = f11; pf1.u[2] = f12; pf1.u[3] = f13;

            __builtin_amdgcn_s_setprio(1);
#pragma unroll
            for (int dt = 0; dt < 2; ++dt) {
                const s16x8 v0 = *(const s16x8*)&Vbuf[cur][vidx[sub][0][dt]];
                const s16x8 v1 = *(const s16x8*)&Vbuf[cur][vidx[sub][1][dt]];
                o_acc[dt] = __builtin_amdgcn_mfma_f32_32x32x16_bf16(v0, pf0.v, o_acc[dt], 0, 0, 0);
                o_acc[dt] = __builtin_amdgcn_mfma_f32_32x32x16_bf16(v1, pf1.v, o_acc[dt], 0, 0, 0);
            }
            __builtin_amdgcn_s_setprio(0);
        }
    }

    float l_tot;
    {
        unsigned a = __float_as_uint(l_run), bq = __float_as_uint(l_run);
        asm volatile("v_permlane32_swap_b32 %0, %1" : "+v"(a), "+v"(bq));
        l_tot = l_run + __uint_as_float(hi ? a : bq);
    }
    const size_t tok = (size_t)(b * Ss + q0 + col);
    if (hi == 0) {
        ML[(size_t)part * (Bb * Ss * Hh) + tok * Hh + h] = make_float2(m_used, l_tot);
    }
    short* obase = Opart + (size_t)part * (Bb * Ss) * Dd + tok * Dd + h * 64;
#pragma unroll
    for (int dt = 0; dt < 2; ++dt) {
#pragma unroll
        for (int c4 = 0; c4 < 4; ++c4) {
            s16x4 ov;
#pragma unroll
            for (int rr = 0; rr < 4; ++rr) ov[rr] = f2bs(o_acc[dt][c4 * 4 + rr]);
            *(s16x4*)&obase[dt * 32 + 8 * c4 + 4 * hi] = ov;
        }
    }
}

// ---------------------------------------------------------------------------
// KSPLIT combine
// ---------------------------------------------------------------------------
__global__ __launch_bounds__(256) void attn_combine(const short* __restrict__ Opart,
                                                    const float2* __restrict__ ML,
                                                    short* __restrict__ Oa) {
    const int tok = blockIdx.x;
    const int t = threadIdx.x;
    const int h = t >> 4;
    const int d = (t & 15) * 4;
    float2 ml[KSPLIT];
    float M = -1e30f;
#pragma unroll
    for (int p = 0; p < KSPLIT; ++p) {
        ml[p] = ML[(size_t)p * (Bb * Ss * Hh) + (size_t)tok * Hh + h];
        M = fmaxf(M, ml[p].x);
    }
    float a[KSPLIT], denom = 0.0f;
#pragma unroll
    for (int p = 0; p < KSPLIT; ++p) {
        a[p] = __builtin_amdgcn_exp2f(ml[p].x - M);
        denom += ml[p].y * a[p];
    }
    const float inv = 1.0f / denom;
    const size_t off = (size_t)tok * Dd + h * 64 + d;
    float acc[4] = {};
#pragma unroll
    for (int p = 0; p < KSPLIT; ++p) {
        const s16x4 o4 = *(const s16x4*)&Opart[(size_t)p * (Bb * Ss) * Dd + off];
#pragma unroll
        for (int r = 0; r < 4; ++r) acc[r] += bs2f(o4[r]) * a[p];
    }
    s16x4 o;
#pragma unroll
    for (int r = 0; r < 4; ++r) o[r] = f2bs(acc[r] * inv);
    *(s16x4*)&Oa[off] = o;
}

// ---------------------------------------------------------------------------
extern "C" void kernel_launch(void* const* d_in, const int* in_sizes, int n_in,
                              void* d_out, int out_size, void* d_ws, size_t ws_size,
                              hipStream_t stream) {
    const float* x    = (const float*)d_in[0];
    const float* mask = (const float*)d_in[1];
    const float* wq   = (const float*)d_in[2];
    const float* wk   = (const float*)d_in[3];
    const float* wv   = (const float*)d_in[4];
    const float* wo   = (const float*)d_in[5];
    const float* w1   = (const float*)d_in[6];
    const float* w2   = (const float*)d_in[7];
    const float* ln1g = (const float*)d_in[8];
    const float* ln1b = (const float*)d_in[9];
    const float* ln2g = (const float*)d_in[10];
    const float* ln2b = (const float*)d_in[11];
    float* out = (float*)d_out;

    char* p = (char*)d_ws;
    short* qkvw_t = (short*)p; p += (size_t)3072 * 1024 * 2;   // 6 MB
    short* wot    = (short*)p; p += (size_t)1024 * 1024 * 2;   // 2 MB
    short* w1t    = (short*)p; p += (size_t)4096 * 1024 * 2;   // 8 MB
    short* w2t    = (short*)p; p += (size_t)1024 * 4096 * 2;   // 8 MB
    short* y_bf   = (short*)p; p += (size_t)4096 * 1024 * 2;   // 8 MB
    short* qkv    = (short*)p; p += (size_t)4096 * 3072 * 2;   // 24 MB
    short* attn_b = (short*)p; p += (size_t)4096 * 1024 * 2;   // 8 MB
    short* y2_bf  = (short*)p; p += (size_t)4096 * 1024 * 2;   // 8 MB
    char*  hregion = p;        p += (size_t)4096 * 4096 * 2;   // 32 MB
    float* msc    = (float*)p; p += (size_t)Bb * Ss * 4;       // 16 KB

    short*  h_bf   = (short*)hregion;
    short*  o_part = (short*)hregion;           // KSPLIT x 8 MB (dead before FFN)
    short*  vt     = y_bf;                      // y_bf dead after QKV GEMM
    float2* ml     = (float2*)qkvw_t;           // qkvw_t dead after QKV GEMM

    const int M = Bb * Ss;  // 4096

    prep<<<3073, 256, 0, stream>>>(wq, wk, wv, wo, w1, w2, mask, qkvw_t, wot, w1t, w2t, msc);
    layernorm_bf16<<<M, 256, 0, stream>>>(x, ln1g, ln1b, y_bf);
    // QKV: 128x128, BK=32, MW=3, grid 768 (3/CU, 1 round)
    gemm_v4<128, 128, 32, 0, 3><<<768, 256, 0, stream>>>(y_bf, qkvw_t, nullptr, qkv, M, 3072, 1024, 24);
    vtranspose<<<dim3(32, 16), 256, 0, stream>>>(qkv, vt);
    // attention: KSPLIT=2, grid 1024 (4/CU, 1 round), XCD-swizzled
    attn_split<<<KSPLIT * 512, 256, 0, stream>>>(qkv, vt, msc, o_part, ml);
    attn_combine<<<M, 256, 0, stream>>>(o_part, ml, attn_b);
    // WO: 64x64, BK=64 (half the drains), MW=4, grid 1024
    gemm_v4<64, 64, 64, 2, 4><<<1024, 256, 0, stream>>>(attn_b, wot, x, out, M, 1024, 1024, 16);
    layernorm_bf16<<<M, 256, 0, stream>>>(out, ln2g, ln2b, y2_bf);
    // W1: 128x128, BK=32, MW=3, grid 1024
    gemm_v4<128, 128, 32, 1, 3><<<1024, 256, 0, stream>>>(y2_bf, w1t, nullptr, h_bf, M, 4096, 1024, 32);
    // W2: 64x64, BK=64, MW=4, grid 1024, K=4096
    gemm_v4<64, 64, 64, 2, 4><<<1024, 256, 0, stream>>>(h_bf, w2t, out, out, M, 1024, 4096, 16);
}